// Round 18
// baseline (109.884 us; speedup 1.0000x reference)
//
#include <hip/hip_runtime.h>

using short8 = __attribute__((ext_vector_type(8))) short;
using f32x4  = __attribute__((ext_vector_type(4))) float;

__device__ __forceinline__ unsigned short f2bf(float f) {
  unsigned u = __float_as_uint(f);
  u += 0x7fffu + ((u >> 16) & 1u);
  return (unsigned short)(u >> 16);
}

// ---------------- Transpose f32 [rows][cols] -> bf16 [cols][rows] (for W) ----------------
__global__ __launch_bounds__(256) void transpose_f2b_kernel(const float* __restrict__ in,
                                                            unsigned short* __restrict__ out,
                                                            int rows, int cols) {
  __shared__ float tile[32][33];
  const int r0 = blockIdx.x * 32, c0 = blockIdx.y * 32;
  const int li = threadIdx.x >> 5, ci = threadIdx.x & 31;
#pragma unroll
  for (int p = 0; p < 4; ++p) {
    int r = li + p * 8;
    tile[r][ci] = in[(size_t)(r0 + r) * cols + c0 + ci];
  }
  __syncthreads();
#pragma unroll
  for (int p = 0; p < 4; ++p) {
    int c = li + p * 8;
    out[(size_t)(c0 + c) * rows + r0 + ci] = f2bf(tile[ci][c]);
  }
}

// ---------------- adj int32 -> bitmask [2048][64] words ----------------
__global__ __launch_bounds__(256) void adjmask_kernel(const int* __restrict__ adj,
                                                      unsigned* __restrict__ adjm) {
  const int wv = (blockIdx.x << 2) + (threadIdx.x >> 6);
  const int lane = threadIdx.x & 63;
  const int row = wv >> 5, j0 = (wv & 31) << 6;
  unsigned long long mask = __ballot(adj[(size_t)row * 2048 + j0 + lane] > 0);
  if (lane == 0) {
    adjm[row * 64 + (j0 >> 5)]     = (unsigned)mask;
    adjm[row * 64 + (j0 >> 5) + 1] = (unsigned)(mask >> 32);
  }
}

// ---------------- Kernel B: fused conv + Wh GEMM + pack + f1/f2 ----------------
// block: 32 gemm rows = (b, n in [jg*32, jg*32+32)); 512 thr = 8 waves (2 rg x 4 cg).
// NEW pack layout (16x16 B-frags): whp[b][ct 24][jc 64][lane 64][8]:
//   lane l elem e = Wh[b][jc*32 + (l>>4)*8 + e][ct*16 + (l&15)]
__global__ __launch_bounds__(512) void gemm_wh3_kernel(const float* __restrict__ x,
                                                       const float* __restrict__ cw,
                                                       const float* __restrict__ cb,
                                                       const unsigned short* __restrict__ Wt,
                                                       const float* __restrict__ a,
                                                       unsigned short* __restrict__ whp,
                                                       float* __restrict__ f1,
                                                       float* __restrict__ f2) {
  __shared__ __align__(16) char lds[49344 + 1792 + 256];
  float* xin = (float*)lds;                                   // [12][1028], 1026 used
  unsigned short* atile = (unsigned short*)lds;               // [32][392] (after conv)
  unsigned short* wtile = (unsigned short*)(lds + 25088);     // [32][392]
  float* cws = (float*)(lds + 49344);                         // 432
  float* cbs = cws + 448;                                     // 12
  float* s1s = (float*)(lds + 49344 + 1792);                  // 32
  float* s2s = s1s + 32;                                      // 32

  const int tid = threadIdx.x;
  const int rb = blockIdx.x;
  const int b = rb >> 6, jg = rb & 63;
  const int r0 = rb << 5;
  const int w = tid >> 6, lane = tid & 63;
  const int rg = w >> 2, cg = w & 3;
  const int il = lane & 15, kg = lane >> 4;

  if (tid < 432) cws[tid] = cw[tid];
  if (tid < 12) cbs[tid] = cb[tid];
  if (tid < 32) { s1s[tid] = 0.f; s2s[tid] = 0.f; }
  const float* xb = x + (size_t)b * 2048 * 12 * 32;
#pragma unroll
  for (int t = 0; t < 12; ++t) {
    for (int i = tid; i < 1026; i += 512) {
      const int gp = jg * 1024 + i - 1;
      float v = 0.f;
      if ((unsigned)gp < 65536u) v = xb[((size_t)(gp >> 5) * 12 + t) * 32 + (gp & 31)];
      xin[t * 1028 + i] = v;
    }
  }
  __syncthreads();

  const int ploc = tid * 2;
  float accv0[12], accv1[12];
#pragma unroll
  for (int to = 0; to < 12; ++to) { accv0[to] = cbs[to]; accv1[to] = cbs[to]; }
#pragma unroll
  for (int ti = 0; ti < 12; ++ti) {
    const float x0 = xin[ti * 1028 + ploc];
    const float x1 = xin[ti * 1028 + ploc + 1];
    const float x2 = xin[ti * 1028 + ploc + 2];
    const float x3 = xin[ti * 1028 + ploc + 3];
#pragma unroll
    for (int to = 0; to < 12; ++to) {
      const float* wp = &cws[(to * 12 + ti) * 3];
      const float w0 = wp[0], w1 = wp[1], w2 = wp[2];
      accv0[to] += x0 * w0 + x1 * w1 + x2 * w2;
      accv1[to] += x1 * w0 + x2 * w1 + x3 * w2;
    }
  }
  __syncthreads();

  {
    const int row = ploc >> 5, f = ploc & 31;
    unsigned* ap32 = (unsigned*)(atile + row * 392 + f);
#pragma unroll
    for (int to = 0; to < 12; ++to) {
      const unsigned lo = f2bf(accv0[to]), hi = f2bf(accv1[to]);
      ap32[to * 16] = lo | (hi << 16);
    }
  }
  __syncthreads();

  f32x4 acc[6];
#pragma unroll
  for (int t = 0; t < 6; ++t) acc[t] = (f32x4){0.f, 0.f, 0.f, 0.f};
  const unsigned short* arow = atile + (rg * 16 + il) * 392 + kg * 8;
#pragma unroll
  for (int kk = 0; kk < 12; ++kk) {
    short8 af = *reinterpret_cast<const short8*>(arow + kk * 32);
#pragma unroll
    for (int t = 0; t < 6; ++t) {
      const int c = cg * 96 + t * 16 + il;
      short8 bf = *reinterpret_cast<const short8*>(Wt + (size_t)c * 384 + kk * 32 + kg * 8);
      acc[t] = __builtin_amdgcn_mfma_f32_16x16x32_bf16(af, bf, acc[t], 0, 0, 0);
    }
  }
  float p1[4] = {0.f, 0.f, 0.f, 0.f}, p2[4] = {0.f, 0.f, 0.f, 0.f};
#pragma unroll
  for (int t = 0; t < 6; ++t) {
    const int c = cg * 96 + t * 16 + il;
    const float a1v = a[c], a2v = a[384 + c];
#pragma unroll
    for (int r = 0; r < 4; ++r) { p1[r] += acc[t][r] * a1v; p2[r] += acc[t][r] * a2v; }
  }
#pragma unroll
  for (int off = 1; off < 16; off <<= 1) {
#pragma unroll
    for (int r = 0; r < 4; ++r) { p1[r] += __shfl_xor(p1[r], off); p2[r] += __shfl_xor(p2[r], off); }
  }
  if (il == 0) {
#pragma unroll
    for (int r = 0; r < 4; ++r) {
      atomicAdd(&s1s[rg * 16 + kg * 4 + r], p1[r]);
      atomicAdd(&s2s[rg * 16 + kg * 4 + r], p2[r]);
    }
  }
#pragma unroll
  for (int t = 0; t < 6; ++t)
#pragma unroll
    for (int r = 0; r < 4; ++r)
      wtile[(rg * 16 + kg * 4 + r) * 392 + cg * 96 + t * 16 + il] = f2bf(acc[t][r]);
  __syncthreads();

  // pack 16x16 B-frag tiles: 24 ct-tiles x 64 lanes; layout [b][ct][jc=jg]
#pragma unroll
  for (int rep = 0; rep < 3; ++rep) {
    const int flat = rep * 512 + tid;
    const int ct = flat >> 6, l = flat & 63;
    const int il16 = l & 15, kg4 = l >> 4;
    short8 v;
#pragma unroll
    for (int e = 0; e < 8; ++e)
      v[e] = (short)wtile[(kg4 * 8 + e) * 392 + ct * 16 + il16];
    *reinterpret_cast<short8*>((char*)whp +
        ((((size_t)b * 24 + ct) * 64 + jg) << 10) + l * 16) = v;
  }
  if (tid < 32) { f1[r0 + tid] = s1s[tid]; f2[r0 + tid] = s2s[tid]; }
}

// ---------------- per-batch max of f2 ----------------
__global__ __launch_bounds__(256) void f2max_kernel(const float* __restrict__ f2,
                                                    float* __restrict__ gmax) {
  __shared__ float wm[4];
  const int b = blockIdx.x;
  const int tid = threadIdx.x;
  float m = -3.0e38f;
  for (int i = tid; i < 2048; i += 256) m = fmaxf(m, f2[b * 2048 + i]);
#pragma unroll
  for (int off = 32; off; off >>= 1) m = fmaxf(m, __shfl_xor(m, off));
  if ((tid & 63) == 0) wm[tid >> 6] = m;
  __syncthreads();
  if (tid == 0) gmax[b] = fmaxf(fmaxf(wm[0], wm[1]), fmaxf(wm[2], wm[3]));
}

// ---------------- Kernel E: attention v11 — 16-row blocks, grid 1024, 3 waves/SIMD ----------------
// grid 1024: ch = bi&1 (192 cols), b = (bi&7)>>1, rowgroup = bi>>3 (16 rows).
// 4 waves = 4 ks (512 j each, 16 steps of 32 j). Wave: 16 rows x 192 cols =
// 12 tiles of 16x16; acc 48 regs. Tiles 0-5 depth-2 dbuf; tiles 6-11 in-step.
// Rolled 8-iter loop (I$-resident). P computed in-register (8 PEL/lane/step).
__global__ __launch_bounds__(256, 3) void attn11_kernel(const float* __restrict__ f1,
                                                        const float* __restrict__ f2,
                                                        const unsigned* __restrict__ adjm,
                                                        const unsigned short* __restrict__ whp,
                                                        const float* __restrict__ gmax,
                                                        float* __restrict__ out) {
  __shared__ float red[4][16][96];      // 24 KB
  __shared__ float dred[64];
  const int bi = blockIdx.x;
  const int ch = bi & 1;
  const int b  = (bi & 7) >> 1;
  const int i0 = (bi >> 3) << 4;
  const int tid = threadIdx.x;
  const int ks = tid >> 6;
  const int lane = tid & 63;
  const int il = lane & 15, kg = lane >> 4;
  const int kg8 = kg * 8;
  const int ig = i0 + il;

  const unsigned* adjr = adjm + (size_t)ig * 64 + ks * 16;   // 16 words = 512 j
  const float* f2b = f2 + b * 2048;
  // base of this wave's frag streams: [b][ct = ch*12][jc = ks*16], lane offset
  const char* pbase = (const char*)whp +
      ((((size_t)b * 24 + ch * 12) * 64 + ks * 16) << 10) + lane * 16;

  const float f1v = f1[b * 2048 + ig];
  const float gm = gmax[b];
  const float mz = f1v + gm;
  const float m  = fmaxf(mz, 0.2f * mz);     // >= true masked row max (lrelu monotone)
  const float Az = f1v - m;
  const float Bz = 0.2f * f1v - m;

  f32x4 acc[12];
#pragma unroll
  for (int t = 0; t < 12; ++t) acc[t] = (f32x4){0.f, 0.f, 0.f, 0.f};
  float denom = 0.f;

  short8 bfD[6], bfE[6], bfS[6];

#define LOADG(AR, KK)                                                                   \
  { _Pragma("unroll")                                                                   \
    for (int tt = 0; tt < 6; ++tt)                                                      \
      AR[tt] = *reinterpret_cast<const short8*>(pbase + (size_t)tt * 65536 +            \
                                                (size_t)(KK) * 1024); }
#define LOADS(KK)                                                                       \
  { _Pragma("unroll")                                                                   \
    for (int tt = 0; tt < 6; ++tt)                                                      \
      bfS[tt] = *reinterpret_cast<const short8*>(pbase + (size_t)(tt + 6) * 65536 +     \
                                                 (size_t)(KK) * 1024); }

#define PEL(GV, BIT, DST)                                                               \
  { const float z_ = Az + (GV);                                                         \
    const float e_ = fmaxf(z_, fmaf((GV), 0.2f, Bz));                                   \
    DST = ((bits_ >> (BIT)) & 1u) ? __expf(e_) : 0.f; }

#define PKBF(HI, LO) (((__float_as_uint(HI) + 0x8000u) & 0xffff0000u) |                 \
                      ((__float_as_uint(LO) + 0x8000u) >> 16))

#define STEPX(AR, KK)                                                                   \
  {                                                                                     \
    LOADS(KK)                                                                           \
    const unsigned word_ = adjr[KK];                                                    \
    const float* fp_ = f2b + ks * 512 + (KK) * 32 + kg8;                                \
    const float4 g0_ = *reinterpret_cast<const float4*>(fp_);                           \
    const float4 g1_ = *reinterpret_cast<const float4*>(fp_ + 4);                       \
    const unsigned bits_ = word_ >> kg8;                                                \
    float p0_, p1_, p2_, p3_, p4_, p5_, p6_, p7_;                                       \
    PEL(g0_.x, 0, p0_)  PEL(g0_.y, 1, p1_)  PEL(g0_.z, 2, p2_)  PEL(g0_.w, 3, p3_)      \
    PEL(g1_.x, 4, p4_)  PEL(g1_.y, 5, p5_)  PEL(g1_.z, 6, p6_)  PEL(g1_.w, 7, p7_)      \
    denom += (((p0_ + p1_) + (p2_ + p3_)) + ((p4_ + p5_) + (p6_ + p7_)));               \
    union { unsigned u[4]; short8 s8; } cc;                                             \
    cc.u[0] = PKBF(p1_, p0_); cc.u[1] = PKBF(p3_, p2_);                                 \
    cc.u[2] = PKBF(p5_, p4_); cc.u[3] = PKBF(p7_, p6_);                                 \
    _Pragma("unroll")                                                                   \
    for (int tt = 0; tt < 6; ++tt)                                                      \
      acc[tt] = __builtin_amdgcn_mfma_f32_16x16x32_bf16(cc.s8, AR[tt], acc[tt], 0, 0, 0); \
    _Pragma("unroll")                                                                   \
    for (int tt = 0; tt < 6; ++tt)                                                      \
      acc[6 + tt] = __builtin_amdgcn_mfma_f32_16x16x32_bf16(cc.s8, bfS[tt], acc[6 + tt], 0, 0, 0); \
  }

  LOADG(bfD, 0)
  LOADG(bfE, 1)
  for (int t = 0; t < 8; ++t) {
    STEPX(bfD, 2 * t)
    if (t < 7) LOADG(bfD, 2 * t + 2)
    STEPX(bfE, 2 * t + 1)
    if (t < 7) LOADG(bfE, 2 * t + 3)
  }
#undef LOADG
#undef LOADS
#undef PEL
#undef PKBF
#undef STEPX

  // ---- epilogue: combine 4 ks accumulators via LDS, normalize, elu, store ----
  float dn = denom + __shfl_xor(denom, 16);
  dn += __shfl_xor(dn, 32);                 // all kg-groups of this il summed
  if (kg == 0) dred[ks * 16 + il] = dn;

#pragma unroll
  for (int rr = 0; rr < 2; ++rr) {
#pragma unroll
    for (int t3 = 0; t3 < 6; ++t3) {
#pragma unroll
      for (int r = 0; r < 4; ++r) {
        const int row = kg * 4 + r;
        red[ks][row][t3 * 16 + il] = acc[rr * 6 + t3][r];
      }
    }
    __syncthreads();
    const size_t ob = ((size_t)b * 2048 + i0) * 384 + ch * 192 + rr * 96;
#pragma unroll
    for (int p = 0; p < 6; ++p) {
      const int idx = p * 256 + tid;
      const int row = idx / 96;
      const int c = idx - row * 96;
      float v = red[0][row][c] + red[1][row][c] + red[2][row][c] + red[3][row][c];
      const float d = dred[row] + dred[16 + row] + dred[32 + row] + dred[48 + row];
      v /= d;
      v = v > 0.f ? v : expm1f(v);
      out[ob + (size_t)row * 384 + c] = v;
    }
    __syncthreads();
  }
}

extern "C" void kernel_launch(void* const* d_in, const int* in_sizes, int n_in,
                              void* d_out, int out_size, void* d_ws, size_t ws_size,
                              hipStream_t stream) {
  const float* x  = (const float*)d_in[0];
  const int* adj  = (const int*)d_in[1];
  const float* W  = (const float*)d_in[2];
  const float* a  = (const float*)d_in[3];
  const float* cw = (const float*)d_in[4];
  const float* cb = (const float*)d_in[5];
  float* out = (float*)d_out;

  char* ws = (char*)d_ws;
  unsigned short* Wt  = (unsigned short*)ws; ws += (size_t)147456 * 2;   // [384][384] bf16 (T)
  unsigned short* whp = (unsigned short*)ws; ws += (size_t)3145728 * 2;  // packed B-frags [b][ct][jc]
  float* f1           = (float*)ws;          ws += (size_t)8192 * 4;
  float* f2           = (float*)ws;          ws += (size_t)8192 * 4;
  unsigned* adjm      = (unsigned*)ws;       ws += (size_t)2048 * 64 * 4;
  float* gmax         = (float*)ws;          ws += 64;

  transpose_f2b_kernel<<<dim3(12, 12), 256, 0, stream>>>(W, Wt, 384, 384);
  adjmask_kernel<<<dim3(16384), 256, 0, stream>>>(adj, adjm);
  gemm_wh3_kernel<<<dim3(256), 512, 0, stream>>>(x, cw, cb, Wt, a, whp, f1, f2);
  f2max_kernel<<<dim3(4), 256, 0, stream>>>(f2, gmax);
  attn11_kernel<<<dim3(1024), 256, 0, stream>>>(f1, f2, adjm, whp, gmax, out);
}

// Round 19
// 99.568 us; speedup vs baseline: 1.1036x; 1.1036x over previous
//
#include <hip/hip_runtime.h>

using short8 = __attribute__((ext_vector_type(8))) short;
using f32x4  = __attribute__((ext_vector_type(4))) float;

__device__ __forceinline__ unsigned short f2bf(float f) {
  unsigned u = __float_as_uint(f);
  u += 0x7fffu + ((u >> 16) & 1u);
  return (unsigned short)(u >> 16);
}

// ---------------- Transpose f32 [rows][cols] -> bf16 [cols][rows] (for W) ----------------
__global__ __launch_bounds__(256) void transpose_f2b_kernel(const float* __restrict__ in,
                                                            unsigned short* __restrict__ out,
                                                            int rows, int cols) {
  __shared__ float tile[32][33];
  const int r0 = blockIdx.x * 32, c0 = blockIdx.y * 32;
  const int li = threadIdx.x >> 5, ci = threadIdx.x & 31;
#pragma unroll
  for (int p = 0; p < 4; ++p) {
    int r = li + p * 8;
    tile[r][ci] = in[(size_t)(r0 + r) * cols + c0 + ci];
  }
  __syncthreads();
#pragma unroll
  for (int p = 0; p < 4; ++p) {
    int c = li + p * 8;
    out[(size_t)(c0 + c) * rows + r0 + ci] = f2bf(tile[ci][c]);
  }
}

// ---------------- adj int32 -> bitmask [2048][64] words ----------------
__global__ __launch_bounds__(256) void adjmask_kernel(const int* __restrict__ adj,
                                                      unsigned* __restrict__ adjm) {
  const int wv = (blockIdx.x << 2) + (threadIdx.x >> 6);
  const int lane = threadIdx.x & 63;
  const int row = wv >> 5, j0 = (wv & 31) << 6;
  unsigned long long mask = __ballot(adj[(size_t)row * 2048 + j0 + lane] > 0);
  if (lane == 0) {
    adjm[row * 64 + (j0 >> 5)]     = (unsigned)mask;
    adjm[row * 64 + (j0 >> 5) + 1] = (unsigned)(mask >> 32);
  }
}

// ---------------- Kernel B: fused conv + Wh GEMM + pack + f1/f2 ----------------
// block: 32 gemm rows = (b, n in [jg*32, jg*32+32)); 512 thr = 8 waves (2 rg x 4 cg).
// pack layout (16x16 B-frags): whp[b][ct 24][jc 64][lane 64][8]:
//   lane l elem e = Wh[b][jc*32 + (l>>4)*8 + e][ct*16 + (l&15)]
__global__ __launch_bounds__(512) void gemm_wh3_kernel(const float* __restrict__ x,
                                                       const float* __restrict__ cw,
                                                       const float* __restrict__ cb,
                                                       const unsigned short* __restrict__ Wt,
                                                       const float* __restrict__ a,
                                                       unsigned short* __restrict__ whp,
                                                       float* __restrict__ f1,
                                                       float* __restrict__ f2) {
  __shared__ __align__(16) char lds[49344 + 1792 + 256];
  float* xin = (float*)lds;                                   // [12][1028], 1026 used
  unsigned short* atile = (unsigned short*)lds;               // [32][392] (after conv)
  unsigned short* wtile = (unsigned short*)(lds + 25088);     // [32][392]
  float* cws = (float*)(lds + 49344);                         // 432
  float* cbs = cws + 448;                                     // 12
  float* s1s = (float*)(lds + 49344 + 1792);                  // 32
  float* s2s = s1s + 32;                                      // 32

  const int tid = threadIdx.x;
  const int rb = blockIdx.x;
  const int b = rb >> 6, jg = rb & 63;
  const int r0 = rb << 5;
  const int w = tid >> 6, lane = tid & 63;
  const int rg = w >> 2, cg = w & 3;
  const int il = lane & 15, kg = lane >> 4;

  if (tid < 432) cws[tid] = cw[tid];
  if (tid < 12) cbs[tid] = cb[tid];
  if (tid < 32) { s1s[tid] = 0.f; s2s[tid] = 0.f; }
  const float* xb = x + (size_t)b * 2048 * 12 * 32;
#pragma unroll
  for (int t = 0; t < 12; ++t) {
    for (int i = tid; i < 1026; i += 512) {
      const int gp = jg * 1024 + i - 1;
      float v = 0.f;
      if ((unsigned)gp < 65536u) v = xb[((size_t)(gp >> 5) * 12 + t) * 32 + (gp & 31)];
      xin[t * 1028 + i] = v;
    }
  }
  __syncthreads();

  const int ploc = tid * 2;
  float accv0[12], accv1[12];
#pragma unroll
  for (int to = 0; to < 12; ++to) { accv0[to] = cbs[to]; accv1[to] = cbs[to]; }
#pragma unroll
  for (int ti = 0; ti < 12; ++ti) {
    const float x0 = xin[ti * 1028 + ploc];
    const float x1 = xin[ti * 1028 + ploc + 1];
    const float x2 = xin[ti * 1028 + ploc + 2];
    const float x3 = xin[ti * 1028 + ploc + 3];
#pragma unroll
    for (int to = 0; to < 12; ++to) {
      const float* wp = &cws[(to * 12 + ti) * 3];
      const float w0 = wp[0], w1 = wp[1], w2 = wp[2];
      accv0[to] += x0 * w0 + x1 * w1 + x2 * w2;
      accv1[to] += x1 * w0 + x2 * w1 + x3 * w2;
    }
  }
  __syncthreads();

  {
    const int row = ploc >> 5, f = ploc & 31;
    unsigned* ap32 = (unsigned*)(atile + row * 392 + f);
#pragma unroll
    for (int to = 0; to < 12; ++to) {
      const unsigned lo = f2bf(accv0[to]), hi = f2bf(accv1[to]);
      ap32[to * 16] = lo | (hi << 16);
    }
  }
  __syncthreads();

  f32x4 acc[6];
#pragma unroll
  for (int t = 0; t < 6; ++t) acc[t] = (f32x4){0.f, 0.f, 0.f, 0.f};
  const unsigned short* arow = atile + (rg * 16 + il) * 392 + kg * 8;
#pragma unroll
  for (int kk = 0; kk < 12; ++kk) {
    short8 af = *reinterpret_cast<const short8*>(arow + kk * 32);
#pragma unroll
    for (int t = 0; t < 6; ++t) {
      const int c = cg * 96 + t * 16 + il;
      short8 bf = *reinterpret_cast<const short8*>(Wt + (size_t)c * 384 + kk * 32 + kg * 8);
      acc[t] = __builtin_amdgcn_mfma_f32_16x16x32_bf16(af, bf, acc[t], 0, 0, 0);
    }
  }
  float p1[4] = {0.f, 0.f, 0.f, 0.f}, p2[4] = {0.f, 0.f, 0.f, 0.f};
#pragma unroll
  for (int t = 0; t < 6; ++t) {
    const int c = cg * 96 + t * 16 + il;
    const float a1v = a[c], a2v = a[384 + c];
#pragma unroll
    for (int r = 0; r < 4; ++r) { p1[r] += acc[t][r] * a1v; p2[r] += acc[t][r] * a2v; }
  }
#pragma unroll
  for (int off = 1; off < 16; off <<= 1) {
#pragma unroll
    for (int r = 0; r < 4; ++r) { p1[r] += __shfl_xor(p1[r], off); p2[r] += __shfl_xor(p2[r], off); }
  }
  if (il == 0) {
#pragma unroll
    for (int r = 0; r < 4; ++r) {
      atomicAdd(&s1s[rg * 16 + kg * 4 + r], p1[r]);
      atomicAdd(&s2s[rg * 16 + kg * 4 + r], p2[r]);
    }
  }
#pragma unroll
  for (int t = 0; t < 6; ++t)
#pragma unroll
    for (int r = 0; r < 4; ++r)
      wtile[(rg * 16 + kg * 4 + r) * 392 + cg * 96 + t * 16 + il] = f2bf(acc[t][r]);
  __syncthreads();

  // pack 16x16 B-frag tiles: 24 ct-tiles x 64 lanes; layout [b][ct][jc=jg]
#pragma unroll
  for (int rep = 0; rep < 3; ++rep) {
    const int flat = rep * 512 + tid;
    const int ct = flat >> 6, l = flat & 63;
    const int il16 = l & 15, kg4 = l >> 4;
    short8 v;
#pragma unroll
    for (int e = 0; e < 8; ++e)
      v[e] = (short)wtile[(kg4 * 8 + e) * 392 + ct * 16 + il16];
    *reinterpret_cast<short8*>((char*)whp +
        ((((size_t)b * 24 + ct) * 64 + jg) << 10) + l * 16) = v;
  }
  if (tid < 32) { f1[r0 + tid] = s1s[tid]; f2[r0 + tid] = s2s[tid]; }
}

// ---------------- per-batch max of f2 ----------------
__global__ __launch_bounds__(256) void f2max_kernel(const float* __restrict__ f2,
                                                    float* __restrict__ gmax) {
  __shared__ float wm[4];
  const int b = blockIdx.x;
  const int tid = threadIdx.x;
  float m = -3.0e38f;
  for (int i = tid; i < 2048; i += 256) m = fmaxf(m, f2[b * 2048 + i]);
#pragma unroll
  for (int off = 32; off; off >>= 1) m = fmaxf(m, __shfl_xor(m, off));
  if ((tid & 63) == 0) wm[tid >> 6] = m;
  __syncthreads();
  if (tid == 0) gmax[b] = fmaxf(fmaxf(wm[0], wm[1]), fmaxf(wm[2], wm[3]));
}

// ---------------- Kernel E: attention v12 — 8-tile waves, full depth-2, 3 waves/SIMD ----------------
// grid 1536: combo = bi % 12 -> b = combo&3, ch = combo>>2 (128 cols); rg = bi/12 (16 rows).
// 4 waves = 4 ks (512 j each, 16 steps of 32 j). Wave: 16 rows x 128 cols = 8 tiles 16x16,
// acc 32 regs. ALL streams depth-2 (B-frags, f2, adj word). Rolled 8-iter loop.
__global__ __launch_bounds__(256, 3) void attn12_kernel(const float* __restrict__ f1,
                                                        const float* __restrict__ f2,
                                                        const unsigned* __restrict__ adjm,
                                                        const unsigned short* __restrict__ whp,
                                                        const float* __restrict__ gmax,
                                                        float* __restrict__ out) {
  __shared__ float red[4][16][128];     // 32 KB
  __shared__ float dred[64];
  const int bi = blockIdx.x;
  const int combo = bi % 12;
  const int b  = combo & 3;
  const int ch = combo >> 2;            // 0..2
  const int i0 = (bi / 12) << 4;
  const int tid = threadIdx.x;
  const int ks = tid >> 6;
  const int lane = tid & 63;
  const int il = lane & 15, kg = lane >> 4;
  const int kg8 = kg * 8;
  const int ig = i0 + il;

  const unsigned* adjr = adjm + (size_t)ig * 64 + ks * 16;   // 16 words = 512 j
  const float* f2b = f2 + b * 2048 + ks * 512 + kg8;
  // wave's frag streams: [b][ct = ch*8 .. +8][jc = ks*16 + step]
  const char* pbase = (const char*)whp +
      ((((size_t)b * 24 + ch * 8) * 64 + ks * 16) << 10) + lane * 16;

  const float f1v = f1[b * 2048 + ig];
  const float gm = gmax[b];
  const float mz = f1v + gm;
  const float m  = fmaxf(mz, 0.2f * mz);     // >= true masked row max (lrelu monotone)
  const float Az = f1v - m;
  const float Bz = 0.2f * f1v - m;

  f32x4 acc[8];
#pragma unroll
  for (int t = 0; t < 8; ++t) acc[t] = (f32x4){0.f, 0.f, 0.f, 0.f};
  float denom = 0.f;

  short8 bA[8], bB[8];
  float4 fA0, fA1, fB0, fB1;
  unsigned wA, wB;

#define LOADB(AR, KK)                                                                   \
  { _Pragma("unroll")                                                                   \
    for (int tt = 0; tt < 8; ++tt)                                                      \
      AR[tt] = *reinterpret_cast<const short8*>(pbase + (size_t)tt * 65536 +            \
                                                (size_t)(KK) * 1024); }

#define PEL(GV, BIT, DST)                                                               \
  { const float z_ = Az + (GV);                                                         \
    const float e_ = fmaxf(z_, fmaf((GV), 0.2f, Bz));                                   \
    DST = ((bits_ >> (BIT)) & 1u) ? __expf(e_) : 0.f; }

#define PKBF(HI, LO) (((__float_as_uint(HI) + 0x8000u) & 0xffff0000u) |                 \
                      ((__float_as_uint(LO) + 0x8000u) >> 16))

#define STEPD(AR, F0, F1, WW, KK, DL)                                                   \
  { const unsigned bits_ = (WW) >> kg8;                                                 \
    float p0_, p1_, p2_, p3_, p4_, p5_, p6_, p7_;                                       \
    PEL(F0.x, 0, p0_)  PEL(F0.y, 1, p1_)  PEL(F0.z, 2, p2_)  PEL(F0.w, 3, p3_)          \
    PEL(F1.x, 4, p4_)  PEL(F1.y, 5, p5_)  PEL(F1.z, 6, p6_)  PEL(F1.w, 7, p7_)          \
    denom += (((p0_ + p1_) + (p2_ + p3_)) + ((p4_ + p5_) + (p6_ + p7_)));               \
    union { unsigned u[4]; short8 s8; } cc;                                             \
    cc.u[0] = PKBF(p1_, p0_); cc.u[1] = PKBF(p3_, p2_);                                 \
    cc.u[2] = PKBF(p5_, p4_); cc.u[3] = PKBF(p7_, p6_);                                 \
    _Pragma("unroll")                                                                   \
    for (int tt = 0; tt < 8; ++tt)                                                      \
      acc[tt] = __builtin_amdgcn_mfma_f32_16x16x32_bf16(cc.s8, AR[tt], acc[tt], 0, 0, 0); \
    if (DL) {                                                                           \
      LOADB(AR, (KK) + 2)                                                               \
      const float* fp_ = f2b + ((KK) + 2) * 32;                                         \
      F0 = *reinterpret_cast<const float4*>(fp_);                                       \
      F1 = *reinterpret_cast<const float4*>(fp_ + 4);                                   \
      WW = adjr[(KK) + 2];                                                              \
    } }

  // prologue: fill both stages
  LOADB(bA, 0) LOADB(bB, 1)
  fA0 = *reinterpret_cast<const float4*>(f2b);
  fA1 = *reinterpret_cast<const float4*>(f2b + 4);
  fB0 = *reinterpret_cast<const float4*>(f2b + 32);
  fB1 = *reinterpret_cast<const float4*>(f2b + 36);
  wA = adjr[0];
  wB = adjr[1];

  for (int t = 0; t < 8; ++t) {
    STEPD(bA, fA0, fA1, wA, 2 * t, (t < 7))
    STEPD(bB, fB0, fB1, wB, 2 * t + 1, (t < 7))
  }
#undef LOADB
#undef PEL
#undef PKBF
#undef STEPD

  // ---- epilogue: combine 4 ks accumulators via LDS, normalize, elu, store ----
  float dn = denom + __shfl_xor(denom, 16);
  dn += __shfl_xor(dn, 32);                 // sum over kg for this il
  if (kg == 0) dred[ks * 16 + il] = dn;

#pragma unroll
  for (int tt = 0; tt < 8; ++tt) {
#pragma unroll
    for (int r = 0; r < 4; ++r) {
      const int row = kg * 4 + r;
      red[ks][row][tt * 16 + il] = acc[tt][r];
    }
  }
  __syncthreads();
  const size_t ob = ((size_t)b * 2048 + i0) * 384 + ch * 128;
#pragma unroll
  for (int p = 0; p < 8; ++p) {
    const int idx = p * 256 + tid;
    const int row = idx >> 7;
    const int c = idx & 127;
    float v = red[0][row][c] + red[1][row][c] + red[2][row][c] + red[3][row][c];
    const float d = dred[row] + dred[16 + row] + dred[32 + row] + dred[48 + row];
    v /= d;
    v = v > 0.f ? v : expm1f(v);
    out[ob + (size_t)row * 384 + c] = v;
  }
}

extern "C" void kernel_launch(void* const* d_in, const int* in_sizes, int n_in,
                              void* d_out, int out_size, void* d_ws, size_t ws_size,
                              hipStream_t stream) {
  const float* x  = (const float*)d_in[0];
  const int* adj  = (const int*)d_in[1];
  const float* W  = (const float*)d_in[2];
  const float* a  = (const float*)d_in[3];
  const float* cw = (const float*)d_in[4];
  const float* cb = (const float*)d_in[5];
  float* out = (float*)d_out;

  char* ws = (char*)d_ws;
  unsigned short* Wt  = (unsigned short*)ws; ws += (size_t)147456 * 2;   // [384][384] bf16 (T)
  unsigned short* whp = (unsigned short*)ws; ws += (size_t)3145728 * 2;  // packed B-frags [b][ct][jc]
  float* f1           = (float*)ws;          ws += (size_t)8192 * 4;
  float* f2           = (float*)ws;          ws += (size_t)8192 * 4;
  unsigned* adjm      = (unsigned*)ws;       ws += (size_t)2048 * 64 * 4;
  float* gmax         = (float*)ws;          ws += 64;

  transpose_f2b_kernel<<<dim3(12, 12), 256, 0, stream>>>(W, Wt, 384, 384);
  adjmask_kernel<<<dim3(16384), 256, 0, stream>>>(adj, adjm);
  gemm_wh3_kernel<<<dim3(256), 512, 0, stream>>>(x, cw, cb, Wt, a, whp, f1, f2);
  f2max_kernel<<<dim3(4), 256, 0, stream>>>(f2, gmax);
  attn12_kernel<<<dim3(1536), 256, 0, stream>>>(f1, f2, adjm, whp, gmax, out);
}

// Round 21
// 88.059 us; speedup vs baseline: 1.2478x; 1.1307x over previous
//
#include <hip/hip_runtime.h>

using short8 = __attribute__((ext_vector_type(8))) short;
using f32x4  = __attribute__((ext_vector_type(4))) float;
using f32x16 = __attribute__((ext_vector_type(16))) float;

__device__ __forceinline__ unsigned short f2bf(float f) {
  unsigned u = __float_as_uint(f);
  u += 0x7fffu + ((u >> 16) & 1u);
  return (unsigned short)(u >> 16);
}

// ---------------- Transpose f32 [rows][cols] -> bf16 [cols][rows] (for W) ----------------
__global__ __launch_bounds__(256) void transpose_f2b_kernel(const float* __restrict__ in,
                                                            unsigned short* __restrict__ out,
                                                            int rows, int cols) {
  __shared__ float tile[32][33];
  const int r0 = blockIdx.x * 32, c0 = blockIdx.y * 32;
  const int li = threadIdx.x >> 5, ci = threadIdx.x & 31;
#pragma unroll
  for (int p = 0; p < 4; ++p) {
    int r = li + p * 8;
    tile[r][ci] = in[(size_t)(r0 + r) * cols + c0 + ci];
  }
  __syncthreads();
#pragma unroll
  for (int p = 0; p < 4; ++p) {
    int c = li + p * 8;
    out[(size_t)(c0 + c) * rows + r0 + ci] = f2bf(tile[ci][c]);
  }
}

// ---------------- adj int32 -> bitmask [2048][64] words ----------------
__global__ __launch_bounds__(256) void adjmask_kernel(const int* __restrict__ adj,
                                                      unsigned* __restrict__ adjm) {
  const int wv = (blockIdx.x << 2) + (threadIdx.x >> 6);
  const int lane = threadIdx.x & 63;
  const int row = wv >> 5, j0 = (wv & 31) << 6;
  unsigned long long mask = __ballot(adj[(size_t)row * 2048 + j0 + lane] > 0);
  if (lane == 0) {
    adjm[row * 64 + (j0 >> 5)]     = (unsigned)mask;
    adjm[row * 64 + (j0 >> 5) + 1] = (unsigned)(mask >> 32);
  }
}

// ---------------- Kernel B: fused conv + Wh GEMM + pack + f1/f2 (16-row blocks) ----------------
// grid 512: b = rb>>7, jg2 = rb&127 -> rows jg2*16..+16. 256 thr = 4 waves (cg = 96 cols each).
// pack layout (32x32x16 B-frags): whp[b][jstep 128][ct32 12][lane 64][8]:
//   lane l elem e = Wh[b][jstep*16 + (l>>5)*8 + e][ct32*32 + (l&31)]   (jstep == jg2)
__global__ __launch_bounds__(256) void gemm_wh4_kernel(const float* __restrict__ x,
                                                       const float* __restrict__ cw,
                                                       const float* __restrict__ cb,
                                                       const unsigned short* __restrict__ Wt,
                                                       const float* __restrict__ a,
                                                       unsigned short* __restrict__ whp,
                                                       float* __restrict__ f1,
                                                       float* __restrict__ f2) {
  __shared__ __align__(16) char lds[24768 + 12544 + 1792 + 128];
  float* xin = (float*)lds;                                   // [12][516], 514 used
  unsigned short* atile = (unsigned short*)lds;               // [16][392] (after conv, overlaps xin)
  unsigned short* wtile = (unsigned short*)(lds + 24768);     // [16][392]
  float* cws = (float*)(lds + 24768 + 12544);                 // 432 floats
  float* cbs = cws + 432;                                     // 12 floats (fits region)
  float* s1s = (float*)(lds + 24768 + 12544 + 1792);          // 16
  float* s2s = s1s + 16;                                      // 16

  const int tid = threadIdx.x;
  const int rb = blockIdx.x;
  const int b = rb >> 7, jg2 = rb & 127;
  const int r0 = rb << 4;
  const int w = tid >> 6, lane = tid & 63;
  const int il = lane & 15, kg = lane >> 4;

  for (int i = tid; i < 432; i += 256) cws[i] = cw[i];   // FIX: 256-thread grid-stride
  if (tid < 12) cbs[tid] = cb[tid];
  if (tid < 16) { s1s[tid] = 0.f; s2s[tid] = 0.f; }
  const float* xb = x + (size_t)b * 2048 * 12 * 32;
#pragma unroll
  for (int t = 0; t < 12; ++t) {
    for (int i = tid; i < 514; i += 256) {
      const int gp = jg2 * 512 + i - 1;
      float v = 0.f;
      if ((unsigned)gp < 65536u) v = xb[((size_t)(gp >> 5) * 12 + t) * 32 + (gp & 31)];
      xin[t * 516 + i] = v;
    }
  }
  __syncthreads();

  // conv: each thread 2 positions x 12 t_o
  const int ploc = tid * 2;
  float accv0[12], accv1[12];
#pragma unroll
  for (int to = 0; to < 12; ++to) { accv0[to] = cbs[to]; accv1[to] = cbs[to]; }
#pragma unroll
  for (int ti = 0; ti < 12; ++ti) {
    const float x0 = xin[ti * 516 + ploc];
    const float x1 = xin[ti * 516 + ploc + 1];
    const float x2 = xin[ti * 516 + ploc + 2];
    const float x3 = xin[ti * 516 + ploc + 3];
#pragma unroll
    for (int to = 0; to < 12; ++to) {
      const float* wp = &cws[(to * 12 + ti) * 3];
      const float w0 = wp[0], w1 = wp[1], w2 = wp[2];
      accv0[to] += x0 * w0 + x1 * w1 + x2 * w2;
      accv1[to] += x1 * w0 + x2 * w1 + x3 * w2;
    }
  }
  __syncthreads();   // all xin reads done before atile overwrite

  {
    const int row = ploc >> 5, f = ploc & 31;
    unsigned* ap32 = (unsigned*)(atile + row * 392 + f);
#pragma unroll
    for (int to = 0; to < 12; ++to) {
      const unsigned lo = f2bf(accv0[to]), hi = f2bf(accv1[to]);
      ap32[to * 16] = lo | (hi << 16);
    }
  }
  __syncthreads();

  // MFMA: 16x384 = A(16x384) @ W(384x384); wave w = cols [w*96, w*96+96)
  f32x4 acc[6];
#pragma unroll
  for (int t = 0; t < 6; ++t) acc[t] = (f32x4){0.f, 0.f, 0.f, 0.f};
  const unsigned short* arow = atile + il * 392 + kg * 8;
#pragma unroll
  for (int kk = 0; kk < 12; ++kk) {
    short8 af = *reinterpret_cast<const short8*>(arow + kk * 32);
#pragma unroll
    for (int t = 0; t < 6; ++t) {
      const int c = w * 96 + t * 16 + il;
      short8 bf = *reinterpret_cast<const short8*>(Wt + (size_t)c * 384 + kk * 32 + kg * 8);
      acc[t] = __builtin_amdgcn_mfma_f32_16x16x32_bf16(af, bf, acc[t], 0, 0, 0);
    }
  }
  // fused f1/f2
  float p1[4] = {0.f, 0.f, 0.f, 0.f}, p2[4] = {0.f, 0.f, 0.f, 0.f};
#pragma unroll
  for (int t = 0; t < 6; ++t) {
    const int c = w * 96 + t * 16 + il;
    const float a1v = a[c], a2v = a[384 + c];
#pragma unroll
    for (int r = 0; r < 4; ++r) { p1[r] += acc[t][r] * a1v; p2[r] += acc[t][r] * a2v; }
  }
#pragma unroll
  for (int off = 1; off < 16; off <<= 1) {
#pragma unroll
    for (int r = 0; r < 4; ++r) { p1[r] += __shfl_xor(p1[r], off); p2[r] += __shfl_xor(p2[r], off); }
  }
  if (il == 0) {
#pragma unroll
    for (int r = 0; r < 4; ++r) {
      atomicAdd(&s1s[kg * 4 + r], p1[r]);
      atomicAdd(&s2s[kg * 4 + r], p2[r]);
    }
  }
#pragma unroll
  for (int t = 0; t < 6; ++t)
#pragma unroll
    for (int r = 0; r < 4; ++r)
      wtile[(kg * 4 + r) * 392 + w * 96 + t * 16 + il] = f2bf(acc[t][r]);
  __syncthreads();

  // pack 32x32x16 B-frags: 12 ct32 tiles x 64 lanes = 768 items, 3 reps x 256
#pragma unroll
  for (int rep = 0; rep < 3; ++rep) {
    const int flat = rep * 256 + tid;
    const int ct32 = flat >> 6, l = flat & 63;
    const int l5 = l & 31, hw2 = l >> 5;
    short8 v;
#pragma unroll
    for (int e = 0; e < 8; ++e)
      v[e] = (short)wtile[(hw2 * 8 + e) * 392 + ct32 * 32 + l5];
    *reinterpret_cast<short8*>((char*)whp +
        ((((size_t)b * 128 + jg2) * 12 + ct32) << 10) + l * 16) = v;
  }
  if (tid < 16) { f1[r0 + tid] = s1s[tid]; f2[r0 + tid] = s2s[tid]; }
}

// ---------------- per-batch max of f2 ----------------
__global__ __launch_bounds__(256) void f2max_kernel(const float* __restrict__ f2,
                                                    float* __restrict__ gmax) {
  __shared__ float wm[4];
  const int b = blockIdx.x;
  const int tid = threadIdx.x;
  float m = -3.0e38f;
  for (int i = tid; i < 2048; i += 256) m = fmaxf(m, f2[b * 2048 + i]);
#pragma unroll
  for (int off = 32; off; off >>= 1) m = fmaxf(m, __shfl_xor(m, off));
  if ((tid & 63) == 0) wm[tid >> 6] = m;
  __syncthreads();
  if (tid == 0) gmax[b] = fmaxf(fmaxf(wm[0], wm[1]), fmaxf(wm[2], wm[3]));
}

// ---------------- Kernel E: attention v13 — 32-row blocks, 32x32 MFMA, full depth-2 ----------------
// grid 768: combo = bi%12 -> b = combo&3, ch = combo>>2 (128 cols); rg = bi/12 -> 32 rows.
// 4 waves = 4 ks (512 j each, 32 steps of 16 j, paired per adj word).
// Wave: 32 rows x 128 cols = 4 tiles 32x32, acc 64 regs; B dbuf 32 regs. Rolled 16-pair loop.
__global__ __launch_bounds__(256, 3) void attn13_kernel(const float* __restrict__ f1,
                                                        const float* __restrict__ f2,
                                                        const unsigned* __restrict__ adjm,
                                                        const unsigned short* __restrict__ whp,
                                                        const float* __restrict__ gmax,
                                                        float* __restrict__ out) {
  __shared__ float red[4][32][64];      // 32 KB
  __shared__ float dred[128];
  const int bi = blockIdx.x;
  const int combo = bi % 12;
  const int b  = combo & 3;
  const int ch = combo >> 2;            // 0..2
  const int i0 = (bi / 12) << 5;
  const int tid = threadIdx.x;
  const int ks = tid >> 6;
  const int lane = tid & 63;
  const int l5 = lane & 31, hw = lane >> 5;
  const int hw8 = hw * 8;
  const int ig = i0 + l5;

  const unsigned* adjr = adjm + (size_t)ig * 64 + ks * 16;   // 16 words = 512 j (2 steps/word)
  const float* f2b = f2 + b * 2048 + ks * 512 + hw8;
  // wave's step blob: [b][jstep = ks*32 + KK][ct32 = ch*4 .. +4] -> contiguous 4 KB
  const char* pbase = (const char*)whp +
      ((((size_t)b * 128 + ks * 32) * 12 + ch * 4) << 10) + lane * 16;

  const float f1v = f1[b * 2048 + ig];
  const float gm = gmax[b];
  const float mz = f1v + gm;
  const float m  = fmaxf(mz, 0.2f * mz);     // >= true masked row max (lrelu monotone)
  const float Az = f1v - m;
  const float Bz = 0.2f * f1v - m;

  const f32x16 zero16 = {0.f,0.f,0.f,0.f,0.f,0.f,0.f,0.f,0.f,0.f,0.f,0.f,0.f,0.f,0.f,0.f};
  f32x16 acc[4];
#pragma unroll
  for (int t = 0; t < 4; ++t) acc[t] = zero16;
  float denom = 0.f;

  short8 bA[4], bB[4];
  float4 fA0, fA1, fB0, fB1;
  unsigned wC, wN;

#define LOADB(AR, KK)                                                                   \
  { _Pragma("unroll")                                                                   \
    for (int tt = 0; tt < 4; ++tt)                                                      \
      AR[tt] = *reinterpret_cast<const short8*>(pbase + (size_t)(KK) * 12288 +          \
                                                (size_t)tt * 1024); }

#define PEL(GV, BIT, DST)                                                               \
  { const float z_ = Az + (GV);                                                         \
    const float e_ = fmaxf(z_, fmaf((GV), 0.2f, Bz));                                   \
    DST = ((bits_ >> (BIT)) & 1u) ? __expf(e_) : 0.f; }

#define PKBF(HI, LO) (((__float_as_uint(HI) + 0x8000u) & 0xffff0000u) |                 \
                      ((__float_as_uint(LO) + 0x8000u) >> 16))

#define STEPD(AR, F0, F1, SH, KK, DL)                                                   \
  { const unsigned bits_ = wC >> ((SH) + hw8);                                          \
    float p0_, p1_, p2_, p3_, p4_, p5_, p6_, p7_;                                       \
    PEL(F0.x, 0, p0_)  PEL(F0.y, 1, p1_)  PEL(F0.z, 2, p2_)  PEL(F0.w, 3, p3_)          \
    PEL(F1.x, 4, p4_)  PEL(F1.y, 5, p5_)  PEL(F1.z, 6, p6_)  PEL(F1.w, 7, p7_)          \
    denom += (((p0_ + p1_) + (p2_ + p3_)) + ((p4_ + p5_) + (p6_ + p7_)));               \
    union { unsigned u[4]; short8 s8; } cc;                                             \
    cc.u[0] = PKBF(p1_, p0_); cc.u[1] = PKBF(p3_, p2_);                                 \
    cc.u[2] = PKBF(p5_, p4_); cc.u[3] = PKBF(p7_, p6_);                                 \
    _Pragma("unroll")                                                                   \
    for (int tt = 0; tt < 4; ++tt)                                                      \
      acc[tt] = __builtin_amdgcn_mfma_f32_32x32x16_bf16(cc.s8, AR[tt], acc[tt], 0, 0, 0); \
    if (DL) {                                                                           \
      LOADB(AR, (KK) + 2)                                                               \
      const float* fp_ = f2b + ((KK) + 2) * 16;                                         \
      F0 = *reinterpret_cast<const float4*>(fp_);                                       \
      F1 = *reinterpret_cast<const float4*>(fp_ + 4);                                   \
    } }

  // prologue
  LOADB(bA, 0) LOADB(bB, 1)
  fA0 = *reinterpret_cast<const float4*>(f2b);
  fA1 = *reinterpret_cast<const float4*>(f2b + 4);
  fB0 = *reinterpret_cast<const float4*>(f2b + 16);
  fB1 = *reinterpret_cast<const float4*>(f2b + 20);
  wC = adjr[0];
  wN = adjr[1];

  for (int t = 0; t < 16; ++t) {
    STEPD(bA, fA0, fA1, 0, 2 * t, (t < 15))
    STEPD(bB, fB0, fB1, 16, 2 * t + 1, (t < 15))
    wC = wN;
    wN = adjr[(t + 2 < 16) ? t + 2 : 15];
  }
#undef LOADB
#undef PEL
#undef PKBF
#undef STEPD

  // ---- epilogue: combine 4 ks accumulators via LDS, normalize, elu, store ----
  float dn = denom + __shfl_xor(denom, 32);   // sum over hw for this l5 row
  if (hw == 0) dred[ks * 32 + l5] = dn;

#pragma unroll
  for (int r = 0; r < 2; ++r) {
#pragma unroll
    for (int tt = 0; tt < 2; ++tt) {
#pragma unroll
      for (int q = 0; q < 16; ++q) {
        const int row = (q & 3) + 8 * (q >> 2) + 4 * hw;
        red[ks][row][tt * 32 + l5] = acc[r * 2 + tt][q];
      }
    }
    __syncthreads();
    const size_t ob = ((size_t)b * 2048 + i0) * 384 + ch * 128 + r * 64;
#pragma unroll
    for (int p = 0; p < 8; ++p) {
      const int idx = p * 256 + tid;
      const int row = idx >> 6;
      const int c = idx & 63;
      float v = red[0][row][c] + red[1][row][c] + red[2][row][c] + red[3][row][c];
      const float d = dred[row] + dred[32 + row] + dred[64 + row] + dred[96 + row];
      v /= d;
      v = v > 0.f ? v : expm1f(v);
      out[ob + (size_t)row * 384 + c] = v;
    }
    __syncthreads();
  }
}

extern "C" void kernel_launch(void* const* d_in, const int* in_sizes, int n_in,
                              void* d_out, int out_size, void* d_ws, size_t ws_size,
                              hipStream_t stream) {
  const float* x  = (const float*)d_in[0];
  const int* adj  = (const int*)d_in[1];
  const float* W  = (const float*)d_in[2];
  const float* a  = (const float*)d_in[3];
  const float* cw = (const float*)d_in[4];
  const float* cb = (const float*)d_in[5];
  float* out = (float*)d_out;

  char* ws = (char*)d_ws;
  unsigned short* Wt  = (unsigned short*)ws; ws += (size_t)147456 * 2;   // [384][384] bf16 (T)
  unsigned short* whp = (unsigned short*)ws; ws += (size_t)3145728 * 2;  // packed B-frags [b][jstep][ct32]
  float* f1           = (float*)ws;          ws += (size_t)8192 * 4;
  float* f2           = (float*)ws;          ws += (size_t)8192 * 4;
  unsigned* adjm      = (unsigned*)ws;       ws += (size_t)2048 * 64 * 4;
  float* gmax         = (float*)ws;          ws += 64;

  transpose_f2b_kernel<<<dim3(12, 12), 256, 0, stream>>>(W, Wt, 384, 384);
  adjmask_kernel<<<dim3(16384), 256, 0, stream>>>(adj, adjm);
  gemm_wh4_kernel<<<dim3(512), 256, 0, stream>>>(x, cw, cb, Wt, a, whp, f1, f2);
  f2max_kernel<<<dim3(4), 256, 0, stream>>>(f2, gmax);
  attn13_kernel<<<dim3(768), 256, 0, stream>>>(f1, f2, adjm, whp, gmax, out);
}

// Round 22
// 79.789 us; speedup vs baseline: 1.3772x; 1.1036x over previous
//
#include <hip/hip_runtime.h>

using short8 = __attribute__((ext_vector_type(8))) short;
using f32x4  = __attribute__((ext_vector_type(4))) float;
using f32x16 = __attribute__((ext_vector_type(16))) float;

__device__ __forceinline__ unsigned short f2bf(float f) {
  unsigned u = __float_as_uint(f);
  u += 0x7fffu + ((u >> 16) & 1u);
  return (unsigned short)(u >> 16);
}

// ---------------- pack W f32 [384k][384c] -> MFMA B-frag blobs wtp[kk 12][ct16 24][lane 64][8] ----------------
// frag (kk,ct): lane l (il=l&15, kg=l>>4) elem e = W[kk*32 + kg*8 + e][ct*16 + il]  (bf16)
__global__ __launch_bounds__(256) void pack_w_kernel(const float* __restrict__ W,
                                                     unsigned short* __restrict__ wtp) {
  const int f = blockIdx.x * 4 + (threadIdx.x >> 6);   // 0..287
  const int l = threadIdx.x & 63;
  const int kk = f / 24, ct = f % 24;
  const int il = l & 15, kg = l >> 4;
  const float* src = W + (size_t)(kk * 32 + kg * 8) * 384 + ct * 16 + il;
  short8 v;
#pragma unroll
  for (int e = 0; e < 8; ++e) v[e] = (short)f2bf(src[(size_t)e * 384]);
  *reinterpret_cast<short8*>((char*)wtp + ((size_t)f << 10) + l * 16) = v;
}

// ---------------- adj int32 -> bitmask [2048][64] words (+ zero f1/f2) ----------------
__global__ __launch_bounds__(256) void adjmask_kernel(const int* __restrict__ adj,
                                                      unsigned* __restrict__ adjm,
                                                      float* __restrict__ f12) {
  if (blockIdx.x < 64) f12[blockIdx.x * 256 + threadIdx.x] = 0.f;   // 16384 floats = f1+f2
  const int wv = (blockIdx.x << 2) + (threadIdx.x >> 6);
  const int lane = threadIdx.x & 63;
  const int row = wv >> 5, j0 = (wv & 31) << 6;
  unsigned long long mask = __ballot(adj[(size_t)row * 2048 + j0 + lane] > 0);
  if (lane == 0) {
    adjm[row * 64 + (j0 >> 5)]     = (unsigned)mask;
    adjm[row * 64 + (j0 >> 5) + 1] = (unsigned)(mask >> 32);
  }
}

// ---------------- Kernel B: fused conv + Wh GEMM + pack + f1/f2 (16-row, col-split) ----------------
// grid 1024: b = rb>>8, jg2 = (rb>>1)&127, ch2 = rb&1 (192 cols). 256 thr = 4 waves (48 cols each).
// pack layout (32x32x16 B-frags): whp[b][jstep 128][ct32 12][lane 64][8]  (jstep == jg2)
__global__ __launch_bounds__(256) void gemm_wh5_kernel(const float* __restrict__ x,
                                                       const float* __restrict__ cw,
                                                       const float* __restrict__ cb,
                                                       const unsigned short* __restrict__ wtp,
                                                       const float* __restrict__ a,
                                                       unsigned short* __restrict__ whp,
                                                       float* __restrict__ f1,
                                                       float* __restrict__ f2) {
  __shared__ __align__(16) char lds[24768 + 6400 + 1792];
  float* xin = (float*)lds;                                   // [12][516], 514 used
  unsigned short* atile = (unsigned short*)lds;               // [16][392] (after conv, overlaps xin)
  unsigned short* wtile = (unsigned short*)(lds + 24768);     // [16][200]
  float* cws = (float*)(lds + 24768 + 6400);                  // 432
  float* cbs = cws + 432;                                     // 12

  const int tid = threadIdx.x;
  const int rb = blockIdx.x;
  const int b = rb >> 8;
  const int jg2 = (rb >> 1) & 127;
  const int ch2 = rb & 1;
  const int r0 = ((b << 7) + jg2) << 4;    // global row base
  const int w = tid >> 6, lane = tid & 63;
  const int il = lane & 15, kg = lane >> 4;

  for (int i = tid; i < 432; i += 256) cws[i] = cw[i];
  if (tid < 12) cbs[tid] = cb[tid];
  const float* xb = x + (size_t)b * 2048 * 12 * 32;
#pragma unroll
  for (int t = 0; t < 12; ++t) {
    for (int i = tid; i < 514; i += 256) {
      const int gp = jg2 * 512 + i - 1;
      float v = 0.f;
      if ((unsigned)gp < 65536u) v = xb[((size_t)(gp >> 5) * 12 + t) * 32 + (gp & 31)];
      xin[t * 516 + i] = v;
    }
  }
  __syncthreads();

  // conv: each thread 2 positions x 12 t_o
  const int ploc = tid * 2;
  float accv0[12], accv1[12];
#pragma unroll
  for (int to = 0; to < 12; ++to) { accv0[to] = cbs[to]; accv1[to] = cbs[to]; }
#pragma unroll
  for (int ti = 0; ti < 12; ++ti) {
    const float x0 = xin[ti * 516 + ploc];
    const float x1 = xin[ti * 516 + ploc + 1];
    const float x2 = xin[ti * 516 + ploc + 2];
    const float x3 = xin[ti * 516 + ploc + 3];
#pragma unroll
    for (int to = 0; to < 12; ++to) {
      const float* wp = &cws[(to * 12 + ti) * 3];
      const float w0 = wp[0], w1 = wp[1], w2 = wp[2];
      accv0[to] += x0 * w0 + x1 * w1 + x2 * w2;
      accv1[to] += x1 * w0 + x2 * w1 + x3 * w2;
    }
  }
  __syncthreads();   // all xin reads done before atile overwrite

  {
    const int row = ploc >> 5, f = ploc & 31;
    unsigned* ap32 = (unsigned*)(atile + row * 392 + f);
#pragma unroll
    for (int to = 0; to < 12; ++to) {
      const unsigned lo = f2bf(accv0[to]), hi = f2bf(accv1[to]);
      ap32[to * 16] = lo | (hi << 16);
    }
  }
  __syncthreads();

  // MFMA: 16 rows x 48 cols per wave; B-frags contiguous from wtp, depth-2 over kk
  f32x4 acc[3];
#pragma unroll
  for (int t = 0; t < 3; ++t) acc[t] = (f32x4){0.f, 0.f, 0.f, 0.f};
  const unsigned short* arow = atile + il * 392 + kg * 8;
  const int ct0 = ch2 * 12 + w * 3;     // first ct16 tile of this wave
  const char* wb = (const char*)wtp + ((size_t)ct0 << 10) + lane * 16;

  short8 bcur[3], bnxt[3];
#pragma unroll
  for (int t = 0; t < 3; ++t)
    bcur[t] = *reinterpret_cast<const short8*>(wb + ((size_t)t << 10));
#pragma unroll
  for (int kk = 0; kk < 12; ++kk) {
    if (kk < 11) {
#pragma unroll
      for (int t = 0; t < 3; ++t)
        bnxt[t] = *reinterpret_cast<const short8*>(wb + (((size_t)(kk + 1) * 24 + t) << 10));
    }
    short8 af = *reinterpret_cast<const short8*>(arow + kk * 32);
#pragma unroll
    for (int t = 0; t < 3; ++t)
      acc[t] = __builtin_amdgcn_mfma_f32_16x16x32_bf16(af, bcur[t], acc[t], 0, 0, 0);
#pragma unroll
    for (int t = 0; t < 3; ++t) bcur[t] = bnxt[t];
  }

  // fused f1/f2 partials over this block's 192 cols -> global atomics
  float p1[4] = {0.f, 0.f, 0.f, 0.f}, p2[4] = {0.f, 0.f, 0.f, 0.f};
#pragma unroll
  for (int t = 0; t < 3; ++t) {
    const int c = (ct0 + t) * 16 + il;
    const float a1v = a[c], a2v = a[384 + c];
#pragma unroll
    for (int r = 0; r < 4; ++r) { p1[r] += acc[t][r] * a1v; p2[r] += acc[t][r] * a2v; }
  }
#pragma unroll
  for (int off = 1; off < 16; off <<= 1) {
#pragma unroll
    for (int r = 0; r < 4; ++r) { p1[r] += __shfl_xor(p1[r], off); p2[r] += __shfl_xor(p2[r], off); }
  }
  if (il == 0) {
#pragma unroll
    for (int r = 0; r < 4; ++r) {
      atomicAdd(&f1[r0 + kg * 4 + r], p1[r]);
      atomicAdd(&f2[r0 + kg * 4 + r], p2[r]);
    }
  }
  // dump bf16 C to wtile (local cols 0..191)
#pragma unroll
  for (int t = 0; t < 3; ++t)
#pragma unroll
    for (int r = 0; r < 4; ++r)
      wtile[(kg * 4 + r) * 200 + (w * 3 + t) * 16 + il] = f2bf(acc[t][r]);
  __syncthreads();

  // pack 32x32x16 B-frags: 6 local ct32 tiles x 64 lanes = 384 items
#pragma unroll
  for (int rep = 0; rep < 2; ++rep) {
    const int flat = rep * 256 + tid;
    if (flat < 384) {
      const int ct32l = flat >> 6, l = flat & 63;
      const int l5 = l & 31, hw2 = l >> 5;
      short8 v;
#pragma unroll
      for (int e = 0; e < 8; ++e)
        v[e] = (short)wtile[(hw2 * 8 + e) * 200 + ct32l * 32 + l5];
      const int ct32g = ch2 * 6 + ct32l;
      *reinterpret_cast<short8*>((char*)whp +
          ((((size_t)b * 128 + jg2) * 12 + ct32g) << 10) + l * 16) = v;
    }
  }
}

// ---------------- per-batch max of f2 ----------------
__global__ __launch_bounds__(256) void f2max_kernel(const float* __restrict__ f2,
                                                    float* __restrict__ gmax) {
  __shared__ float wm[4];
  const int b = blockIdx.x;
  const int tid = threadIdx.x;
  float m = -3.0e38f;
  for (int i = tid; i < 2048; i += 256) m = fmaxf(m, f2[b * 2048 + i]);
#pragma unroll
  for (int off = 32; off; off >>= 1) m = fmaxf(m, __shfl_xor(m, off));
  if ((tid & 63) == 0) wm[tid >> 6] = m;
  __syncthreads();
  if (tid == 0) gmax[b] = fmaxf(fmaxf(wm[0], wm[1]), fmaxf(wm[2], wm[3]));
}

// ---------------- Kernel E: attention v13 — 32-row blocks, 32x32 MFMA, full depth-2 ----------------
// grid 768: combo = bi%12 -> b = combo&3, ch = combo>>2 (128 cols); rg = bi/12 -> 32 rows.
__global__ __launch_bounds__(256, 3) void attn13_kernel(const float* __restrict__ f1,
                                                        const float* __restrict__ f2,
                                                        const unsigned* __restrict__ adjm,
                                                        const unsigned short* __restrict__ whp,
                                                        const float* __restrict__ gmax,
                                                        float* __restrict__ out) {
  __shared__ float red[4][32][64];      // 32 KB
  __shared__ float dred[128];
  const int bi = blockIdx.x;
  const int combo = bi % 12;
  const int b  = combo & 3;
  const int ch = combo >> 2;            // 0..2
  const int i0 = (bi / 12) << 5;
  const int tid = threadIdx.x;
  const int ks = tid >> 6;
  const int lane = tid & 63;
  const int l5 = lane & 31, hw = lane >> 5;
  const int hw8 = hw * 8;
  const int ig = i0 + l5;

  const unsigned* adjr = adjm + (size_t)ig * 64 + ks * 16;
  const float* f2b = f2 + b * 2048 + ks * 512 + hw8;
  const char* pbase = (const char*)whp +
      ((((size_t)b * 128 + ks * 32) * 12 + ch * 4) << 10) + lane * 16;

  const float f1v = f1[b * 2048 + ig];
  const float gm = gmax[b];
  const float mz = f1v + gm;
  const float m  = fmaxf(mz, 0.2f * mz);
  const float Az = f1v - m;
  const float Bz = 0.2f * f1v - m;

  const f32x16 zero16 = {0.f,0.f,0.f,0.f,0.f,0.f,0.f,0.f,0.f,0.f,0.f,0.f,0.f,0.f,0.f,0.f};
  f32x16 acc[4];
#pragma unroll
  for (int t = 0; t < 4; ++t) acc[t] = zero16;
  float denom = 0.f;

  short8 bA[4], bB[4];
  float4 fA0, fA1, fB0, fB1;
  unsigned wC, wN;

#define LOADB(AR, KK)                                                                   \
  { _Pragma("unroll")                                                                   \
    for (int tt = 0; tt < 4; ++tt)                                                      \
      AR[tt] = *reinterpret_cast<const short8*>(pbase + (size_t)(KK) * 12288 +          \
                                                (size_t)tt * 1024); }

#define PEL(GV, BIT, DST)                                                               \
  { const float z_ = Az + (GV);                                                         \
    const float e_ = fmaxf(z_, fmaf((GV), 0.2f, Bz));                                   \
    DST = ((bits_ >> (BIT)) & 1u) ? __expf(e_) : 0.f; }

#define PKBF(HI, LO) (((__float_as_uint(HI) + 0x8000u) & 0xffff0000u) |                 \
                      ((__float_as_uint(LO) + 0x8000u) >> 16))

#define STEPD(AR, F0, F1, SH, KK, DL)                                                   \
  { const unsigned bits_ = wC >> ((SH) + hw8);                                          \
    float p0_, p1_, p2_, p3_, p4_, p5_, p6_, p7_;                                       \
    PEL(F0.x, 0, p0_)  PEL(F0.y, 1, p1_)  PEL(F0.z, 2, p2_)  PEL(F0.w, 3, p3_)          \
    PEL(F1.x, 4, p4_)  PEL(F1.y, 5, p5_)  PEL(F1.z, 6, p6_)  PEL(F1.w, 7, p7_)          \
    denom += (((p0_ + p1_) + (p2_ + p3_)) + ((p4_ + p5_) + (p6_ + p7_)));               \
    union { unsigned u[4]; short8 s8; } cc;                                             \
    cc.u[0] = PKBF(p1_, p0_); cc.u[1] = PKBF(p3_, p2_);                                 \
    cc.u[2] = PKBF(p5_, p4_); cc.u[3] = PKBF(p7_, p6_);                                 \
    _Pragma("unroll")                                                                   \
    for (int tt = 0; tt < 4; ++tt)                                                      \
      acc[tt] = __builtin_amdgcn_mfma_f32_32x32x16_bf16(cc.s8, AR[tt], acc[tt], 0, 0, 0); \
    if (DL) {                                                                           \
      LOADB(AR, (KK) + 2)                                                               \
      const float* fp_ = f2b + ((KK) + 2) * 16;                                         \
      F0 = *reinterpret_cast<const float4*>(fp_);                                       \
      F1 = *reinterpret_cast<const float4*>(fp_ + 4);                                   \
    } }

  LOADB(bA, 0) LOADB(bB, 1)
  fA0 = *reinterpret_cast<const float4*>(f2b);
  fA1 = *reinterpret_cast<const float4*>(f2b + 4);
  fB0 = *reinterpret_cast<const float4*>(f2b + 16);
  fB1 = *reinterpret_cast<const float4*>(f2b + 20);
  wC = adjr[0];
  wN = adjr[1];

  for (int t = 0; t < 16; ++t) {
    STEPD(bA, fA0, fA1, 0, 2 * t, (t < 15))
    STEPD(bB, fB0, fB1, 16, 2 * t + 1, (t < 15))
    wC = wN;
    wN = adjr[(t + 2 < 16) ? t + 2 : 15];
  }
#undef LOADB
#undef PEL
#undef PKBF
#undef STEPD

  float dn = denom + __shfl_xor(denom, 32);
  if (hw == 0) dred[ks * 32 + l5] = dn;

#pragma unroll
  for (int r = 0; r < 2; ++r) {
#pragma unroll
    for (int tt = 0; tt < 2; ++tt) {
#pragma unroll
      for (int q = 0; q < 16; ++q) {
        const int row = (q & 3) + 8 * (q >> 2) + 4 * hw;
        red[ks][row][tt * 32 + l5] = acc[r * 2 + tt][q];
      }
    }
    __syncthreads();
    const size_t ob = ((size_t)b * 2048 + i0) * 384 + ch * 128 + r * 64;
#pragma unroll
    for (int p = 0; p < 8; ++p) {
      const int idx = p * 256 + tid;
      const int row = idx >> 6;
      const int c = idx & 63;
      float v = red[0][row][c] + red[1][row][c] + red[2][row][c] + red[3][row][c];
      const float d = dred[row] + dred[32 + row] + dred[64 + row] + dred[96 + row];
      v /= d;
      v = v > 0.f ? v : expm1f(v);
      out[ob + (size_t)row * 384 + c] = v;
    }
    __syncthreads();
  }
}

extern "C" void kernel_launch(void* const* d_in, const int* in_sizes, int n_in,
                              void* d_out, int out_size, void* d_ws, size_t ws_size,
                              hipStream_t stream) {
  const float* x  = (const float*)d_in[0];
  const int* adj  = (const int*)d_in[1];
  const float* W  = (const float*)d_in[2];
  const float* a  = (const float*)d_in[3];
  const float* cw = (const float*)d_in[4];
  const float* cb = (const float*)d_in[5];
  float* out = (float*)d_out;

  char* ws = (char*)d_ws;
  unsigned short* wtp = (unsigned short*)ws; ws += (size_t)147456 * 2;   // packed W B-frags [kk][ct16]
  unsigned short* whp = (unsigned short*)ws; ws += (size_t)3145728 * 2;  // packed Wh B-frags [b][jstep][ct32]
  float* f1           = (float*)ws;          ws += (size_t)8192 * 4;
  float* f2           = (float*)ws;          ws += (size_t)8192 * 4;
  unsigned* adjm      = (unsigned*)ws;       ws += (size_t)2048 * 64 * 4;
  float* gmax         = (float*)ws;          ws += 64;

  pack_w_kernel<<<dim3(72), 256, 0, stream>>>(W, wtp);
  adjmask_kernel<<<dim3(16384), 256, 0, stream>>>(adj, adjm, f1);
  gemm_wh5_kernel<<<dim3(1024), 256, 0, stream>>>(x, cw, cb, wtp, a, whp, f1, f2);
  f2max_kernel<<<dim3(4), 256, 0, stream>>>(f2, gmax);
  attn13_kernel<<<dim3(768), 256, 0, stream>>>(f1, f2, adjm, whp, gmax, out);
}